// Round 18
// baseline (667.978 us; speedup 1.0000x reference)
//
#include <hip/hip_runtime.h>
#include <hip/hip_bf16.h>

// Sumformer inner block -- R18: 4-wave blocks, MF=8 (128 neurons x 64 nodes
// per wave). R17 (501us) is act-LDS-read bound: LDS-per-FLOP = 1/MF, and
// MF=4 gave LDS 768cy vs MFMA 310cy per CU-tile (util 39% == 310/768).
// MF=8 halves act-LDS per FLOP -> near-balanced (384 vs 310). acc[8][4]=128
// +af32+bf16 ~ 196 VGPR -- 256-thread blocks have allocated >128 before
// (m97:164); 512-thread blocks cap at 128 (R15/16). Weights stay global->reg
// (1 lane per element, R17-proven); K-loop barrier-free (R17-proven).

typedef __attribute__((ext_vector_type(8))) short bf16x8;
typedef __attribute__((ext_vector_type(4))) float f32x4;

#define N_NODES 131072
#define NUM_G   1024

__device__ __forceinline__ float lrelu_f(float v) { return v >= 0.f ? v : 0.01f * v; }
__device__ __forceinline__ short f2bs(float f) {
  union { __hip_bfloat16 h; short s; } q; q.h = __float2bfloat16(f); return q.s;
}
__device__ __forceinline__ float bs2f(unsigned short u) {
  unsigned x = ((unsigned)u) << 16; return __uint_as_float(x);
}
__device__ __forceinline__ void gll16(const __hip_bfloat16* g, char* l) {
  __builtin_amdgcn_global_load_lds((const __attribute__((address_space(1))) void*)g,
                                   (__attribute__((address_space(3))) void*)l, 16, 0, 0);
}

__global__ void sentinel(float* out, float v) {
  if (blockIdx.x == 0 && threadIdx.x == 0) out[0] = v;
}

// Old layout (for gemm_mfma only): WT[p][k] = bf16(W[k][p])
__global__ void wt_conv(const float* __restrict__ W, __hip_bfloat16* __restrict__ WT, int K, int P) {
  __shared__ float tile[32][33];
  const int p0 = blockIdx.x << 5, k0 = blockIdx.y << 5;
  const int tx = threadIdx.x & 31, ty = threadIdx.x >> 5;
#pragma unroll
  for (int i = 0; i < 4; ++i) {
    int r = ty + (i << 3);
    tile[r][tx] = W[(size_t)(k0 + r) * P + p0 + tx];
  }
  __syncthreads();
#pragma unroll
  for (int i = 0; i < 4; ++i) {
    int r = ty + (i << 3);
    WT[(size_t)(p0 + r) * K + k0 + tx] = __float2bfloat16(tile[tx][r]);
  }
}

// Slab-granule layout: granule (k>>3)*P + p holds W[8*(k>>3)..+7][p] bf16x8.
template<int SHIFT>   // SHIFT = log2(P)
__global__ void wt_convC(const float* __restrict__ W, __hip_bfloat16* __restrict__ WTc) {
  int idx = blockIdx.x * 256 + threadIdx.x;
  int p = idx & ((1 << SHIFT) - 1);
  int k = idx >> SHIFT;
  WTc[((size_t)((k >> 3) << SHIFT) + p) * 8 + (k & 7)] = __float2bfloat16(W[idx]);
}

__global__ void sigma_fin(const float* __restrict__ sums,
                          const int* __restrict__ ids,
                          __hip_bfloat16* __restrict__ sigma) {
  int g = blockIdx.x;
  int k = threadIdx.x;
  int lo = 0, hi = N_NODES;
  while (lo < hi) { int m = (lo + hi) >> 1; if (ids[m] < g) lo = m + 1; else hi = m; }
  int s = lo;
  hi = N_NODES;
  while (lo < hi) { int m = (lo + hi) >> 1; if (ids[m] < g + 1) lo = m + 1; else hi = m; }
  int e = lo;
  float c = (float)(e - s);
  sigma[g * 256 + k] = __float2bfloat16(sums[g * 256 + k] / fmaxf(c, 1.f));
}

// R8 gemm (green): only for sh = sigma @ agWT + agb  [1024x256 x 256x512]
template<int ACT, int BF16OUT>
__global__ __launch_bounds__(256)
void gemm_mfma(const __hip_bfloat16* __restrict__ A,
               const __hip_bfloat16* __restrict__ BT,
               const float* __restrict__ bias,
               void* __restrict__ out, int K, int P) {
  __shared__ __attribute__((aligned(128))) char smem[81920];
  const int tid  = threadIdx.x;
  const int lane = tid & 63;
  const int wave = tid >> 6;
  const int bcol = blockIdx.x << 7;
  const int brow = blockIdx.y << 7;
  const int wm = (wave >> 1) << 6;
  const int wn = (wave & 1) << 6;
  const int lrow = lane >> 2;
  const int gc   = (lane & 3) ^ ((lane >> 3) & 3);
  f32x4 acc[4][4] = {};
  const int nt = K >> 5;
  auto STAGE = [&](int t) {
    char* sA = smem + (t % 5) * 16384;
    char* sB = sA + 8192;
    const int k0 = t << 5;
#pragma unroll
    for (int i = 0; i < 2; ++i) {
      int seg = (wave << 1) + i;
      int row = (seg << 4) + lrow;
      gll16(A + (size_t)(brow + row) * K + (k0 + (gc << 3)), sA + (seg << 10));
      gll16(BT + (size_t)(bcol + row) * K + (k0 + (gc << 3)), sB + (seg << 10));
    }
  };
  STAGE(0); STAGE(1); STAGE(2);
  const int r15 = lane & 15;
  const int c   = lane >> 4;
  for (int t = 0; t < nt; ++t) {
    if (t + 3 < nt) STAGE(t + 3);
    const int rem = nt - 1 - t;
    if (rem >= 3)      asm volatile("s_waitcnt vmcnt(12)" ::: "memory");
    else if (rem == 2) asm volatile("s_waitcnt vmcnt(8)"  ::: "memory");
    else if (rem == 1) asm volatile("s_waitcnt vmcnt(4)"  ::: "memory");
    else               asm volatile("s_waitcnt vmcnt(0)"  ::: "memory");
    __builtin_amdgcn_s_barrier();
    __builtin_amdgcn_sched_barrier(0);
    char* sA = smem + (t % 5) * 16384;
    char* sB = sA + 8192;
    bf16x8 af[4], bfv[4];
#pragma unroll
    for (int f = 0; f < 4; ++f) {
      int ar = wm + (f << 4) + r15;
      af[f]  = *reinterpret_cast<const bf16x8*>(sA + ar * 64 + ((c ^ ((ar >> 1) & 3)) << 4));
      int br = wn + (f << 4) + r15;
      bfv[f] = *reinterpret_cast<const bf16x8*>(sB + br * 64 + ((c ^ ((br >> 1) & 3)) << 4));
    }
#pragma unroll
    for (int fm = 0; fm < 4; ++fm)
#pragma unroll
      for (int fn = 0; fn < 4; ++fn)
        acc[fm][fn] = __builtin_amdgcn_mfma_f32_16x16x32_bf16(af[fm], bfv[fn], acc[fm][fn], 0, 0, 0);
  }
  const int hi4 = (lane >> 4) << 2;
#pragma unroll
  for (int fn = 0; fn < 4; ++fn) {
    int col = bcol + wn + (fn << 4) + r15;
    float bv = bias[col];
#pragma unroll
    for (int fm = 0; fm < 4; ++fm) {
      int row0 = brow + wm + (fm << 4) + hi4;
#pragma unroll
      for (int r = 0; r < 4; ++r) {
        float v = acc[fm][fn][r] + bv;
        if (ACT) v = lrelu_f(v);
        size_t oidx = (size_t)(row0 + r) * P + col;
        if (BF16OUT) reinterpret_cast<__hip_bfloat16*>(out)[oidx] = __float2bfloat16(v);
        else         reinterpret_cast<float*>(out)[oidx] = v;
      }
    }
  }
}

// ---------------- fused layer-chain v9: 4 waves, MF = PW/16 = P/64 --------
// act LDS [64 nodes][512 k] bf16: addr(nd,kc) = nd*1024 + ((kc^(nd&7))<<4).
// A-frags from slab-granule weights: lane (khi,r15), frag mi of tile t =
// granule (4t+khi)*P + p0w + mi*16 + r15 (16B/lane, 1 lane per element).
// K-loop barrier-free. MODE: 0 bias+lrelu->act; 1 +sh gather;
// 2 ge-final+seg-sum; 3 final->d_out.
template<int K, int P, int MODE>
__device__ __forceinline__ void layer9(
    char* actmem, const __hip_bfloat16* __restrict__ WTs,
    const float* __restrict__ bias, const float* __restrict__ sh,
    const int* __restrict__ ids, float* __restrict__ gout, int nbase, int tid) {
  const int w = tid >> 6, lane = tid & 63;
  const int r15 = lane & 15, khi = lane >> 4;
  constexpr int PW = P >> 2;           // neurons per wave (128/64/32)
  constexpr int MF = PW >> 4;          // m-frags per wave (8/4/2)
  constexpr int NT = K >> 5;
  const int p0w = w * PW;
  const bf16x8* __restrict__ WTg = reinterpret_cast<const bf16x8*>(WTs);
  const size_t gb = (size_t)khi * P + p0w + r15;   // granule offset for t=0

  f32x4 acc[MF][4];
#pragma unroll
  for (int a = 0; a < MF; ++a)
#pragma unroll
    for (int b = 0; b < 4; ++b) acc[a][b] = f32x4{0.f, 0.f, 0.f, 0.f};

#pragma unroll
  for (int t = 0; t < NT; ++t) {
    bf16x8 af[MF], bf[4];
#pragma unroll
    for (int mi = 0; mi < MF; ++mi)
      af[mi] = WTg[gb + (size_t)(t << 2) * P + (mi << 4)];
    const int chsw = ((t << 2) + khi) ^ (r15 & 7);   // (nd&7)==(r15&7)
#pragma unroll
    for (int ni = 0; ni < 4; ++ni) {
      int nd = (ni << 4) + r15;
      bf[ni] = *reinterpret_cast<const bf16x8*>(actmem + (nd << 10) + (chsw << 4));
    }
#pragma unroll
    for (int mi = 0; mi < MF; ++mi)
#pragma unroll
      for (int ni = 0; ni < 4; ++ni)
        acc[mi][ni] = __builtin_amdgcn_mfma_f32_16x16x32_bf16(af[mi], bf[ni], acc[mi][ni], 0, 0, 0);
  }

  // ---- epilogue: C/D col=node(lane&15), row=neuron((lane>>4)*4+reg) ----
  if constexpr (MODE == 3) {
#pragma unroll
    for (int mi = 0; mi < MF; ++mi) {
      const int pb = p0w + (mi << 4) + (khi << 2);   // P=128, MF=2
      f32x4 bv = *reinterpret_cast<const f32x4*>(bias + pb);
#pragma unroll
      for (int ni = 0; ni < 4; ++ni) {
        int nd = (ni << 4) + r15;
        f32x4 v = acc[mi][ni] + bv;
        *reinterpret_cast<f32x4*>(gout + ((size_t)(nbase + nd) << 7) + pb) = v;
      }
    }
  } else {
    __syncthreads();   // all waves done reading act
#pragma unroll
    for (int mi = 0; mi < MF; ++mi) {
      const int pb = p0w + (mi << 4) + (khi << 2);
      f32x4 bv = *reinterpret_cast<const f32x4*>(bias + pb);
#pragma unroll
      for (int ni = 0; ni < 4; ++ni) {
        int nd = (ni << 4) + r15;
        f32x4 v = acc[mi][ni] + bv;
        if constexpr (MODE == 1) {
          int g = ids[nbase + nd];
          f32x4 s = *reinterpret_cast<const f32x4*>(sh + ((size_t)g << 9) + pb);
          v = v + s;
        }
        short4 u;
        u.x = f2bs(lrelu_f(v[0])); u.y = f2bs(lrelu_f(v[1]));
        u.z = f2bs(lrelu_f(v[2])); u.w = f2bs(lrelu_f(v[3]));
        int ch = (pb >> 3) ^ (nd & 7);
        *reinterpret_cast<short4*>(actmem + (nd << 10) + (ch << 4) + ((pb & 4) << 1)) = u;
      }
    }
    __syncthreads();   // act visible to next layer / seg-sum

    if constexpr (MODE == 2) {
      // fused segment-sum of ne (=act[64][256]) -> atomicAdd into gout=sums
      const int c = tid;   // 0..255
      float a = 0.f;
      int gp = ids[nbase];
      for (int r = 0; r < 64; ++r) {
        int ch = (c >> 3) ^ (r & 7);
        unsigned short uv = *reinterpret_cast<const unsigned short*>(
            actmem + (r << 10) + (ch << 4) + ((c & 7) << 1));
        float v = bs2f(uv);
        int g = ids[nbase + r];
        if (g != gp) { atomicAdd(gout + ((size_t)gp << 8) + c, a); a = 0.f; gp = g; }
        a += v;
      }
      atomicAdd(gout + ((size_t)gp << 8) + c, a);
    }
  }
}

template<int PSI>
__global__ __launch_bounds__(256)
void fused_chain9(const float* __restrict__ x, const int* __restrict__ bids,
                  const __hip_bfloat16* __restrict__ Wa, const float* __restrict__ ba,
                  const __hip_bfloat16* __restrict__ Wb, const float* __restrict__ bb,
                  const __hip_bfloat16* __restrict__ Wc, const float* __restrict__ bc,
                  const __hip_bfloat16* __restrict__ Wd, const float* __restrict__ bd,
                  const __hip_bfloat16* __restrict__ We, const float* __restrict__ be,
                  const float* __restrict__ sh, float* __restrict__ gout) {
  __shared__ __attribute__((aligned(128))) char actmem[65536];
  const int tid = threadIdx.x;
  const int nbase = blockIdx.x << 6;

  // stage x[64][128] f32 -> act bf16 swizzled (1024 granules, 4/thread)
#pragma unroll
  for (int i = 0; i < 4; ++i) {
    int L = (i << 8) + tid;
    int n = L >> 4, c = L & 15;
    const float* xp = x + (((size_t)(nbase + n)) << 7) + (c << 3);
    float4 v0 = *reinterpret_cast<const float4*>(xp);
    float4 v1 = *reinterpret_cast<const float4*>(xp + 4);
    bf16x8 pk;
    pk[0] = f2bs(v0.x); pk[1] = f2bs(v0.y); pk[2] = f2bs(v0.z); pk[3] = f2bs(v0.w);
    pk[4] = f2bs(v1.x); pk[5] = f2bs(v1.y); pk[6] = f2bs(v1.z); pk[7] = f2bs(v1.w);
    *reinterpret_cast<bf16x8*>(actmem + (n << 10) + ((c ^ (n & 7)) << 4)) = pk;
  }
  __syncthreads();

  if constexpr (PSI == 0) {
    layer9<128, 512, 0>(actmem, Wa, ba, nullptr, bids, nullptr, nbase, tid);
    layer9<512, 512, 0>(actmem, Wb, bb, nullptr, bids, nullptr, nbase, tid);
    layer9<512, 512, 0>(actmem, Wc, bc, nullptr, bids, nullptr, nbase, tid);
    layer9<512, 256, 2>(actmem, Wd, bd, nullptr, bids, gout, nbase, tid);
  } else {
    layer9<128, 512, 1>(actmem, Wa, ba, sh, bids, nullptr, nbase, tid);
    layer9<512, 512, 0>(actmem, Wb, bb, nullptr, bids, nullptr, nbase, tid);
    layer9<512, 512, 0>(actmem, Wc, bc, nullptr, bids, nullptr, nbase, tid);
    layer9<512, 512, 0>(actmem, Wd, bd, nullptr, bids, nullptr, nbase, tid);
    layer9<512, 128, 3>(actmem, We, be, nullptr, bids, gout, nbase, tid);
  }
}

extern "C" void kernel_launch(void* const* d_in, const int* in_sizes, int n_in,
                              void* d_out, int out_size, void* d_ws, size_t ws_size,
                              hipStream_t stream) {
  const float* x      = (const float*)d_in[0];
  const int*   bids   = (const int*)  d_in[1];
  const float* ge_W0  = (const float*)d_in[2];
  const float* ge_b0  = (const float*)d_in[3];
  const float* ge_Wh  = (const float*)d_in[4];
  const float* ge_bh  = (const float*)d_in[5];
  const float* ge_Wo  = (const float*)d_in[6];
  const float* ge_bo  = (const float*)d_in[7];
  const float* in_W   = (const float*)d_in[8];
  const float* in_b   = (const float*)d_in[9];
  const float* ag_W   = (const float*)d_in[10];
  const float* ag_b   = (const float*)d_in[11];
  const float* psi_Wh = (const float*)d_in[12];
  const float* psi_bh = (const float*)d_in[13];
  const float* psi_Wo = (const float*)d_in[14];
  const float* psi_bo = (const float*)d_in[15];

  char* ws = (char*)d_ws;
  __hip_bfloat16* geW0C   = (__hip_bfloat16*)(ws + 0);        // slab [16][512]
  __hip_bfloat16* geWh0C  = (__hip_bfloat16*)(ws + 131072);   // [64][512]
  __hip_bfloat16* geWh1C  = (__hip_bfloat16*)(ws + 655360);
  __hip_bfloat16* geWoC   = (__hip_bfloat16*)(ws + 1179648);  // [64][256]
  __hip_bfloat16* inWC    = (__hip_bfloat16*)(ws + 1441792);  // [16][512]
  __hip_bfloat16* agWT    = (__hip_bfloat16*)(ws + 1572864);  // OLD layout [512][256]
  __hip_bfloat16* psiWh0C = (__hip_bfloat16*)(ws + 1835008);
  __hip_bfloat16* psiWh1C = (__hip_bfloat16*)(ws + 2359296);
  __hip_bfloat16* psiWh2C = (__hip_bfloat16*)(ws + 2883584);
  __hip_bfloat16* psiWoC  = (__hip_bfloat16*)(ws + 3407872);  // [64][128]
  __hip_bfloat16* sigma   = (__hip_bfloat16*)(ws + 3538944);  // [1024][256] bf16
  float*          sh      = (float*)         (ws + 4063232);  // [1024][512] f32
  float*          sums    = (float*)         (ws + 6160384);  // [1024][256] f32

  if (ws_size < 7340032) {
    sentinel<<<1, 64, 0, stream>>>((float*)d_out, 100000000.f + (float)(ws_size / 1024));
    return;
  }

  dim3 blk(256);
  hipMemsetAsync(sums, 0, NUM_G * 256 * sizeof(float), stream);

  // ---- weight conversions ----
  wt_convC<9><<<256,  blk, 0, stream>>>(ge_W0,           geW0C);
  wt_convC<9><<<1024, blk, 0, stream>>>(ge_Wh,           geWh0C);
  wt_convC<9><<<1024, blk, 0, stream>>>(ge_Wh + 262144,  geWh1C);
  wt_convC<8><<<512,  blk, 0, stream>>>(ge_Wo,           geWoC);
  wt_convC<9><<<256,  blk, 0, stream>>>(in_W,            inWC);
  wt_conv<<<dim3(16, 8), blk, 0, stream>>>(ag_W, agWT, 256, 512);   // old layout
  wt_convC<9><<<1024, blk, 0, stream>>>(psi_Wh,          psiWh0C);
  wt_convC<9><<<1024, blk, 0, stream>>>(psi_Wh + 262144, psiWh1C);
  wt_convC<9><<<1024, blk, 0, stream>>>(psi_Wh + 524288, psiWh2C);
  wt_convC<7><<<256,  blk, 0, stream>>>(psi_Wo,          psiWoC);

  // ---- ge chain fused (writes segment sums) ----
  fused_chain9<0><<<N_NODES / 64, blk, 0, stream>>>(
      x, bids, geW0C, ge_b0, geWh0C, ge_bh, geWh1C, ge_bh + 512, geWoC, ge_bo,
      nullptr, nullptr, nullptr, sums);

  // ---- sigma; sh = sigma @ agWT + agb ----
  sigma_fin<<<NUM_G, blk, 0, stream>>>(sums, bids, sigma);
  gemm_mfma<0, 0><<<dim3(4, 8), blk, 0, stream>>>(sigma, agWT, ag_b, sh, 256, 512);

  // ---- psi chain fused (writes d_out) ----
  fused_chain9<1><<<N_NODES / 64, blk, 0, stream>>>(
      x, bids, inWC, in_b, psiWh0C, psi_bh, psiWh1C, psi_bh + 512,
      psiWh2C, psi_bh + 1024, psiWoC, psi_bo, sh, (float*)d_out);
}

// Round 19
// 432.224 us; speedup vs baseline: 1.5454x; 1.5454x over previous
//
#include <hip/hip_runtime.h>
#include <hip/hip_bf16.h>

// Sumformer inner block -- R19: PW=128 (R18 intensity) + explicit weight-frag
// register double-buffer + launch_bounds(256,2) + setprio.
// R18 post-mortem: PW=128 halves LDS/FLOP (right move) but lost to latency
// exposure (1 wave/SIMD resident phases; weight-L2 loads unhidden; MfmaUtil
// 29.7 vs 64% L2-bound ceiling). R19 hides the L2 latency by loading af(t+1)
// BEFORE tile t's MFMAs (ping-pong regs, full unroll = static indexing) and
// budgets 256 VGPR/wave via (256,2). acc128 + af64 + bf16 + addr ~ 210.

typedef __attribute__((ext_vector_type(8))) short bf16x8;
typedef __attribute__((ext_vector_type(4))) float f32x4;

#define N_NODES 131072
#define NUM_G   1024

__device__ __forceinline__ float lrelu_f(float v) { return v >= 0.f ? v : 0.01f * v; }
__device__ __forceinline__ short f2bs(float f) {
  union { __hip_bfloat16 h; short s; } q; q.h = __float2bfloat16(f); return q.s;
}
__device__ __forceinline__ float bs2f(unsigned short u) {
  unsigned x = ((unsigned)u) << 16; return __uint_as_float(x);
}
__device__ __forceinline__ void gll16(const __hip_bfloat16* g, char* l) {
  __builtin_amdgcn_global_load_lds((const __attribute__((address_space(1))) void*)g,
                                   (__attribute__((address_space(3))) void*)l, 16, 0, 0);
}

__global__ void sentinel(float* out, float v) {
  if (blockIdx.x == 0 && threadIdx.x == 0) out[0] = v;
}

// Old layout (for gemm_mfma only): WT[p][k] = bf16(W[k][p])
__global__ void wt_conv(const float* __restrict__ W, __hip_bfloat16* __restrict__ WT, int K, int P) {
  __shared__ float tile[32][33];
  const int p0 = blockIdx.x << 5, k0 = blockIdx.y << 5;
  const int tx = threadIdx.x & 31, ty = threadIdx.x >> 5;
#pragma unroll
  for (int i = 0; i < 4; ++i) {
    int r = ty + (i << 3);
    tile[r][tx] = W[(size_t)(k0 + r) * P + p0 + tx];
  }
  __syncthreads();
#pragma unroll
  for (int i = 0; i < 4; ++i) {
    int r = ty + (i << 3);
    WT[(size_t)(p0 + r) * K + k0 + tx] = __float2bfloat16(tile[tx][r]);
  }
}

// Slab-granule layout: granule (k>>3)*P + p holds W[8*(k>>3)..+7][p] bf16x8.
template<int SHIFT>   // SHIFT = log2(P)
__global__ void wt_convC(const float* __restrict__ W, __hip_bfloat16* __restrict__ WTc) {
  int idx = blockIdx.x * 256 + threadIdx.x;
  int p = idx & ((1 << SHIFT) - 1);
  int k = idx >> SHIFT;
  WTc[((size_t)((k >> 3) << SHIFT) + p) * 8 + (k & 7)] = __float2bfloat16(W[idx]);
}

__global__ void sigma_fin(const float* __restrict__ sums,
                          const int* __restrict__ ids,
                          __hip_bfloat16* __restrict__ sigma) {
  int g = blockIdx.x;
  int k = threadIdx.x;
  int lo = 0, hi = N_NODES;
  while (lo < hi) { int m = (lo + hi) >> 1; if (ids[m] < g) lo = m + 1; else hi = m; }
  int s = lo;
  hi = N_NODES;
  while (lo < hi) { int m = (lo + hi) >> 1; if (ids[m] < g + 1) lo = m + 1; else hi = m; }
  int e = lo;
  float c = (float)(e - s);
  sigma[g * 256 + k] = __float2bfloat16(sums[g * 256 + k] / fmaxf(c, 1.f));
}

// R8 gemm (green): only for sh = sigma @ agWT + agb  [1024x256 x 256x512]
template<int ACT, int BF16OUT>
__global__ __launch_bounds__(256)
void gemm_mfma(const __hip_bfloat16* __restrict__ A,
               const __hip_bfloat16* __restrict__ BT,
               const float* __restrict__ bias,
               void* __restrict__ out, int K, int P) {
  __shared__ __attribute__((aligned(128))) char smem[81920];
  const int tid  = threadIdx.x;
  const int lane = tid & 63;
  const int wave = tid >> 6;
  const int bcol = blockIdx.x << 7;
  const int brow = blockIdx.y << 7;
  const int wm = (wave >> 1) << 6;
  const int wn = (wave & 1) << 6;
  const int lrow = lane >> 2;
  const int gc   = (lane & 3) ^ ((lane >> 3) & 3);
  f32x4 acc[4][4] = {};
  const int nt = K >> 5;
  auto STAGE = [&](int t) {
    char* sA = smem + (t % 5) * 16384;
    char* sB = sA + 8192;
    const int k0 = t << 5;
#pragma unroll
    for (int i = 0; i < 2; ++i) {
      int seg = (wave << 1) + i;
      int row = (seg << 4) + lrow;
      gll16(A + (size_t)(brow + row) * K + (k0 + (gc << 3)), sA + (seg << 10));
      gll16(BT + (size_t)(bcol + row) * K + (k0 + (gc << 3)), sB + (seg << 10));
    }
  };
  STAGE(0); STAGE(1); STAGE(2);
  const int r15 = lane & 15;
  const int c   = lane >> 4;
  for (int t = 0; t < nt; ++t) {
    if (t + 3 < nt) STAGE(t + 3);
    const int rem = nt - 1 - t;
    if (rem >= 3)      asm volatile("s_waitcnt vmcnt(12)" ::: "memory");
    else if (rem == 2) asm volatile("s_waitcnt vmcnt(8)"  ::: "memory");
    else if (rem == 1) asm volatile("s_waitcnt vmcnt(4)"  ::: "memory");
    else               asm volatile("s_waitcnt vmcnt(0)"  ::: "memory");
    __builtin_amdgcn_s_barrier();
    __builtin_amdgcn_sched_barrier(0);
    char* sA = smem + (t % 5) * 16384;
    char* sB = sA + 8192;
    bf16x8 af[4], bfv[4];
#pragma unroll
    for (int f = 0; f < 4; ++f) {
      int ar = wm + (f << 4) + r15;
      af[f]  = *reinterpret_cast<const bf16x8*>(sA + ar * 64 + ((c ^ ((ar >> 1) & 3)) << 4));
      int br = wn + (f << 4) + r15;
      bfv[f] = *reinterpret_cast<const bf16x8*>(sB + br * 64 + ((c ^ ((br >> 1) & 3)) << 4));
    }
#pragma unroll
    for (int fm = 0; fm < 4; ++fm)
#pragma unroll
      for (int fn = 0; fn < 4; ++fn)
        acc[fm][fn] = __builtin_amdgcn_mfma_f32_16x16x32_bf16(af[fm], bfv[fn], acc[fm][fn], 0, 0, 0);
  }
  const int hi4 = (lane >> 4) << 2;
#pragma unroll
  for (int fn = 0; fn < 4; ++fn) {
    int col = bcol + wn + (fn << 4) + r15;
    float bv = bias[col];
#pragma unroll
    for (int fm = 0; fm < 4; ++fm) {
      int row0 = brow + wm + (fm << 4) + hi4;
#pragma unroll
      for (int r = 0; r < 4; ++r) {
        float v = acc[fm][fn][r] + bv;
        if (ACT) v = lrelu_f(v);
        size_t oidx = (size_t)(row0 + r) * P + col;
        if (BF16OUT) reinterpret_cast<__hip_bfloat16*>(out)[oidx] = __float2bfloat16(v);
        else         reinterpret_cast<float*>(out)[oidx] = v;
      }
    }
  }
}

// ---------------- fused layer-chain v10: 4 waves, PW=P/4, af reg-dbuf ------
// act LDS [64 nodes][512 k] bf16: addr(nd,kc) = nd*1024 + ((kc^(nd&7))<<4).
// A-frags from slab-granule weights, PREFETCHED one k32-tile ahead into a
// ping-pong register set. K-loop barrier-free (act read-only, no LDS writes).
// MODE: 0 bias+lrelu->act; 1 +sh gather; 2 ge-final+seg-sum; 3 final->d_out.
template<int K, int P, int MODE>
__device__ __forceinline__ void layer10(
    char* actmem, const __hip_bfloat16* __restrict__ WTs,
    const float* __restrict__ bias, const float* __restrict__ sh,
    const int* __restrict__ ids, float* __restrict__ gout, int nbase, int tid) {
  const int w = tid >> 6, lane = tid & 63;
  const int r15 = lane & 15, khi = lane >> 4;
  constexpr int PW = P >> 2;           // neurons per wave (128/64/32)
  constexpr int MF = PW >> 4;          // m-frags per wave (8/4/2)
  constexpr int NT = K >> 5;
  const int p0w = w * PW;
  const bf16x8* __restrict__ WTg = reinterpret_cast<const bf16x8*>(WTs);
  const size_t gb = (size_t)khi * P + p0w + r15;   // granule offset for t=0

  f32x4 acc[MF][4];
#pragma unroll
  for (int a = 0; a < MF; ++a)
#pragma unroll
    for (int b = 0; b < 4; ++b) acc[a][b] = f32x4{0.f, 0.f, 0.f, 0.f};

  bf16x8 afA[MF], afB[MF];
#pragma unroll
  for (int mi = 0; mi < MF; ++mi)      // prologue: af(0)
    afA[mi] = WTg[gb + (mi << 4)];

#pragma unroll
  for (int t = 0; t < NT; ++t) {
    bf16x8* cur = (t & 1) ? afB : afA;   // static (full unroll)
    bf16x8* nxt = (t & 1) ? afA : afB;
    if (t + 1 < NT) {                    // prefetch af(t+1): hides L2 latency
#pragma unroll
      for (int mi = 0; mi < MF; ++mi)
        nxt[mi] = WTg[gb + (size_t)((t + 1) << 2) * P + (mi << 4)];
    }
    bf16x8 bf[4];
    const int chsw = ((t << 2) + khi) ^ (r15 & 7);   // (nd&7)==(r15&7)
#pragma unroll
    for (int ni = 0; ni < 4; ++ni) {
      int nd = (ni << 4) + r15;
      bf[ni] = *reinterpret_cast<const bf16x8*>(actmem + (nd << 10) + (chsw << 4));
    }
    __builtin_amdgcn_s_setprio(1);
#pragma unroll
    for (int mi = 0; mi < MF; ++mi)
#pragma unroll
      for (int ni = 0; ni < 4; ++ni)
        acc[mi][ni] = __builtin_amdgcn_mfma_f32_16x16x32_bf16(cur[mi], bf[ni], acc[mi][ni], 0, 0, 0);
    __builtin_amdgcn_s_setprio(0);
  }

  // ---- epilogue: C/D col=node(lane&15), row=neuron((lane>>4)*4+reg) ----
  if constexpr (MODE == 3) {
#pragma unroll
    for (int mi = 0; mi < MF; ++mi) {
      const int pb = p0w + (mi << 4) + (khi << 2);   // P=128, MF=2
      f32x4 bv = *reinterpret_cast<const f32x4*>(bias + pb);
#pragma unroll
      for (int ni = 0; ni < 4; ++ni) {
        int nd = (ni << 4) + r15;
        f32x4 v = acc[mi][ni] + bv;
        *reinterpret_cast<f32x4*>(gout + ((size_t)(nbase + nd) << 7) + pb) = v;
      }
    }
  } else {
    __syncthreads();   // all waves done reading act
#pragma unroll
    for (int mi = 0; mi < MF; ++mi) {
      const int pb = p0w + (mi << 4) + (khi << 2);
      f32x4 bv = *reinterpret_cast<const f32x4*>(bias + pb);
#pragma unroll
      for (int ni = 0; ni < 4; ++ni) {
        int nd = (ni << 4) + r15;
        f32x4 v = acc[mi][ni] + bv;
        if constexpr (MODE == 1) {
          int g = ids[nbase + nd];
          f32x4 s = *reinterpret_cast<const f32x4*>(sh + ((size_t)g << 9) + pb);
          v = v + s;
        }
        short4 u;
        u.x = f2bs(lrelu_f(v[0])); u.y = f2bs(lrelu_f(v[1]));
        u.z = f2bs(lrelu_f(v[2])); u.w = f2bs(lrelu_f(v[3]));
        int ch = (pb >> 3) ^ (nd & 7);
        *reinterpret_cast<short4*>(actmem + (nd << 10) + (ch << 4) + ((pb & 4) << 1)) = u;
      }
    }
    __syncthreads();   // act visible to next layer / seg-sum

    if constexpr (MODE == 2) {
      // fused segment-sum of ne (=act[64][256]) -> atomicAdd into gout=sums
      const int c = tid;   // 0..255
      float a = 0.f;
      int gp = ids[nbase];
      for (int r = 0; r < 64; ++r) {
        int ch = (c >> 3) ^ (r & 7);
        unsigned short uv = *reinterpret_cast<const unsigned short*>(
            actmem + (r << 10) + (ch << 4) + ((c & 7) << 1));
        float v = bs2f(uv);
        int g = ids[nbase + r];
        if (g != gp) { atomicAdd(gout + ((size_t)gp << 8) + c, a); a = 0.f; gp = g; }
        a += v;
      }
      atomicAdd(gout + ((size_t)gp << 8) + c, a);
    }
  }
}

template<int PSI>
__global__ __launch_bounds__(256, 2)
void fused_chain10(const float* __restrict__ x, const int* __restrict__ bids,
                   const __hip_bfloat16* __restrict__ Wa, const float* __restrict__ ba,
                   const __hip_bfloat16* __restrict__ Wb, const float* __restrict__ bb,
                   const __hip_bfloat16* __restrict__ Wc, const float* __restrict__ bc,
                   const __hip_bfloat16* __restrict__ Wd, const float* __restrict__ bd,
                   const __hip_bfloat16* __restrict__ We, const float* __restrict__ be,
                   const float* __restrict__ sh, float* __restrict__ gout) {
  __shared__ __attribute__((aligned(128))) char actmem[65536];
  const int tid = threadIdx.x;
  const int nbase = blockIdx.x << 6;

  // stage x[64][128] f32 -> act bf16 swizzled (1024 granules, 4/thread)
#pragma unroll
  for (int i = 0; i < 4; ++i) {
    int L = (i << 8) + tid;
    int n = L >> 4, c = L & 15;
    const float* xp = x + (((size_t)(nbase + n)) << 7) + (c << 3);
    float4 v0 = *reinterpret_cast<const float4*>(xp);
    float4 v1 = *reinterpret_cast<const float4*>(xp + 4);
    bf16x8 pk;
    pk[0] = f2bs(v0.x); pk[1] = f2bs(v0.y); pk[2] = f2bs(v0.z); pk[3] = f2bs(v0.w);
    pk[4] = f2bs(v1.x); pk[5] = f2bs(v1.y); pk[6] = f2bs(v1.z); pk[7] = f2bs(v1.w);
    *reinterpret_cast<bf16x8*>(actmem + (n << 10) + ((c ^ (n & 7)) << 4)) = pk;
  }
  __syncthreads();

  if constexpr (PSI == 0) {
    layer10<128, 512, 0>(actmem, Wa, ba, nullptr, bids, nullptr, nbase, tid);
    layer10<512, 512, 0>(actmem, Wb, bb, nullptr, bids, nullptr, nbase, tid);
    layer10<512, 512, 0>(actmem, Wc, bc, nullptr, bids, nullptr, nbase, tid);
    layer10<512, 256, 2>(actmem, Wd, bd, nullptr, bids, gout, nbase, tid);
  } else {
    layer10<128, 512, 1>(actmem, Wa, ba, sh, bids, nullptr, nbase, tid);
    layer10<512, 512, 0>(actmem, Wb, bb, nullptr, bids, nullptr, nbase, tid);
    layer10<512, 512, 0>(actmem, Wc, bc, nullptr, bids, nullptr, nbase, tid);
    layer10<512, 512, 0>(actmem, Wd, bd, nullptr, bids, nullptr, nbase, tid);
    layer10<512, 128, 3>(actmem, We, be, nullptr, bids, gout, nbase, tid);
  }
}

extern "C" void kernel_launch(void* const* d_in, const int* in_sizes, int n_in,
                              void* d_out, int out_size, void* d_ws, size_t ws_size,
                              hipStream_t stream) {
  const float* x      = (const float*)d_in[0];
  const int*   bids   = (const int*)  d_in[1];
  const float* ge_W0  = (const float*)d_in[2];
  const float* ge_b0  = (const float*)d_in[3];
  const float* ge_Wh  = (const float*)d_in[4];
  const float* ge_bh  = (const float*)d_in[5];
  const float* ge_Wo  = (const float*)d_in[6];
  const float* ge_bo  = (const float*)d_in[7];
  const float* in_W   = (const float*)d_in[8];
  const float* in_b   = (const float*)d_in[9];
  const float* ag_W   = (const float*)d_in[10];
  const float* ag_b   = (const float*)d_in[11];
  const float* psi_Wh = (const float*)d_in[12];
  const float* psi_bh = (const float*)d_in[13];
  const float* psi_Wo = (const float*)d_in[14];
  const float* psi_bo = (const float*)d_in[15];

  char* ws = (char*)d_ws;
  __hip_bfloat16* geW0C   = (__hip_bfloat16*)(ws + 0);        // slab [16][512]
  __hip_bfloat16* geWh0C  = (__hip_bfloat16*)(ws + 131072);   // [64][512]
  __hip_bfloat16* geWh1C  = (__hip_bfloat16*)(ws + 655360);
  __hip_bfloat16* geWoC   = (__hip_bfloat16*)(ws + 1179648);  // [64][256]
  __hip_bfloat16* inWC    = (__hip_bfloat16*)(ws + 1441792);  // [16][512]
  __hip_bfloat16* agWT    = (__hip_bfloat16*)(ws + 1572864);  // OLD layout [512][256]
  __hip_bfloat16* psiWh0C = (__hip_bfloat16*)(ws + 1835008);
  __hip_bfloat16* psiWh1C = (__hip_bfloat16*)(ws + 2359296);
  __hip_bfloat16* psiWh2C = (__hip_bfloat16*)(ws + 2883584);
  __hip_bfloat16* psiWoC  = (__hip_bfloat16*)(ws + 3407872);  // [64][128]
  __hip_bfloat16* sigma   = (__hip_bfloat16*)(ws + 3538944);  // [1024][256] bf16
  float*          sh      = (float*)         (ws + 4063232);  // [1024][512] f32
  float*          sums    = (float*)         (ws + 6160384);  // [1024][256] f32

  if (ws_size < 7340032) {
    sentinel<<<1, 64, 0, stream>>>((float*)d_out, 100000000.f + (float)(ws_size / 1024));
    return;
  }

  dim3 blk(256);
  hipMemsetAsync(sums, 0, NUM_G * 256 * sizeof(float), stream);

  // ---- weight conversions ----
  wt_convC<9><<<256,  blk, 0, stream>>>(ge_W0,           geW0C);
  wt_convC<9><<<1024, blk, 0, stream>>>(ge_Wh,           geWh0C);
  wt_convC<9><<<1024, blk, 0, stream>>>(ge_Wh + 262144,  geWh1C);
  wt_convC<8><<<512,  blk, 0, stream>>>(ge_Wo,           geWoC);
  wt_convC<9><<<256,  blk, 0, stream>>>(in_W,            inWC);
  wt_conv<<<dim3(16, 8), blk, 0, stream>>>(ag_W, agWT, 256, 512);   // old layout
  wt_convC<9><<<1024, blk, 0, stream>>>(psi_Wh,          psiWh0C);
  wt_convC<9><<<1024, blk, 0, stream>>>(psi_Wh + 262144, psiWh1C);
  wt_convC<9><<<1024, blk, 0, stream>>>(psi_Wh + 524288, psiWh2C);
  wt_convC<7><<<256,  blk, 0, stream>>>(psi_Wo,          psiWoC);

  // ---- ge chain fused (writes segment sums) ----
  fused_chain10<0><<<N_NODES / 64, blk, 0, stream>>>(
      x, bids, geW0C, ge_b0, geWh0C, ge_bh, geWh1C, ge_bh + 512, geWoC, ge_bo,
      nullptr, nullptr, nullptr, sums);

  // ---- sigma; sh = sigma @ agWT + agb ----
  sigma_fin<<<NUM_G, blk, 0, stream>>>(sums, bids, sigma);
  gemm_mfma<0, 0><<<dim3(4, 8), blk, 0, stream>>>(sigma, agWT, ag_b, sh, 256, 512);

  // ---- psi chain fused (writes d_out) ----
  fused_chain10<1><<<N_NODES / 64, blk, 0, stream>>>(
      x, bids, inWC, in_b, psiWh0C, psi_bh, psiWh1C, psi_bh + 512,
      psiWh2C, psi_bh + 1024, psiWoC, psi_bo, sh, (float*)d_out);
}